// Round 1
// baseline (64.897 us; speedup 1.0000x reference)
//
#include <hip/hip_runtime.h>

// DistanceTransform closed form:
//   d(p)  = Chebyshev (L_inf) distance to nearest seed (replicate-pad => clamp)
//   out(p)= 0 if d==0 else (d-1) - 0.35*log(a*w1 + b*w2)
// where a = # of 4-neighbors (clamped) with d < d(p), b = # diagonal neighbors,
// w1 = exp(-1/0.35), w2 = exp(-sqrt(2)/0.35).
// d computed separably: per-row 1D L1 DT g[j][x], then d(y,x)=min_j max(|y-j|, g[j][x]).

// ---------------- Kernel 1: per-row 1D L1 distance transform ----------------
// One wave (64 lanes) per row; 4 pixels per lane; shuffle scans.
__global__ __launch_bounds__(64) void k_rowdt(const float* __restrict__ img,
                                              unsigned char* __restrict__ g) {
    const int r    = blockIdx.x;   // global row 0..511 (2 images x 256 rows)
    const int lane = threadIdx.x;  // 0..63
    const float4 v = reinterpret_cast<const float4*>(img + (size_t)r * 256)[lane];
    const int x0 = lane * 4;
    const int NEG = -1000;
    const int POS = 100000;

    // forward: nearest seed index to the left (inclusive) via max-scan
    int m0 = (v.x != 0.0f) ? (x0    ) : NEG;
    int m1 = (v.y != 0.0f) ? (x0 + 1) : NEG;
    int m2 = (v.z != 0.0f) ? (x0 + 2) : NEG;
    int m3 = (v.w != 0.0f) ? (x0 + 3) : NEG;
    int p0 = m0;
    int p1 = max(p0, m1);
    int p2 = max(p1, m2);
    int p3 = max(p2, m3);
    int t = p3;
    #pragma unroll
    for (int off = 1; off < 64; off <<= 1) {
        int u = __shfl_up(t, off);
        if (lane >= off) t = max(t, u);
    }
    int e = __shfl_up(t, 1);
    if (lane == 0) e = NEG;
    const int f0 = (x0    ) - max(e, p0);
    const int f1 = (x0 + 1) - max(e, p1);
    const int f2 = (x0 + 2) - max(e, p2);
    const int f3 = (x0 + 3) - max(e, p3);

    // backward: nearest seed index to the right (inclusive) via min-scan
    int n0 = (v.x != 0.0f) ? (x0    ) : POS;
    int n1 = (v.y != 0.0f) ? (x0 + 1) : POS;
    int n2 = (v.z != 0.0f) ? (x0 + 2) : POS;
    int n3 = (v.w != 0.0f) ? (x0 + 3) : POS;
    int s3 = n3;
    int s2 = min(n2, s3);
    int s1 = min(n1, s2);
    int s0 = min(n0, s1);
    int tb = s0;
    #pragma unroll
    for (int off = 1; off < 64; off <<= 1) {
        int u = __shfl_down(tb, off);
        if (lane < 64 - off) tb = min(tb, u);
    }
    int eb = __shfl_down(tb, 1);
    if (lane == 63) eb = POS;
    const int b0 = min(eb, s0) - (x0    );
    const int b1 = min(eb, s1) - (x0 + 1);
    const int b2 = min(eb, s2) - (x0 + 2);
    const int b3 = min(eb, s3) - (x0 + 3);

    // g = min(forward, backward), clamped to 255 (>=256 can never win in k_cheb:
    // row 0 of each image has a seed at x=0, so true d <= 255 always)
    unsigned int packed =
          (unsigned int)min(min(f0, b0), 255)
        | ((unsigned int)min(min(f1, b1), 255) << 8)
        | ((unsigned int)min(min(f2, b2), 255) << 16)
        | ((unsigned int)min(min(f3, b3), 255) << 24);
    reinterpret_cast<unsigned int*>(g + (size_t)r * 256)[lane] = packed;
}

// ------------- Kernel 2: Chebyshev DT via separable min-max combine ---------
// One block per output row (n,y); thread x loops over source rows j.
// g for one image = 64 KiB -> L2-resident; loads are fully coalesced.
__global__ __launch_bounds__(256) void k_cheb(const unsigned char* __restrict__ g,
                                              unsigned char* __restrict__ d) {
    const int b = blockIdx.x;            // n*256 + y
    const int y = b & 255;
    const unsigned char* gn = g + ((b >> 8) << 16);
    const int x = threadIdx.x;
    int best = 255;
    #pragma unroll 8
    for (int j = 0; j < 256; ++j) {
        int gv = gn[(j << 8) + x];
        int ay = abs(y - j);             // wave-uniform -> scalar
        best = min(best, max(ay, gv));
    }
    d[(b << 8) + x] = (unsigned char)best;
}

// ---------------- Kernel 3: epilogue (counts + log) -------------------------
__global__ __launch_bounds__(256) void k_out(const unsigned char* __restrict__ d,
                                             float* __restrict__ out) {
    const int p   = blockIdx.x * 256 + threadIdx.x;  // 0..131071
    const int rem = p & 65535;
    const int y   = rem >> 8;
    const int x   = rem & 255;
    const unsigned char* dn = d + ((p >> 16) << 16);
    const int dp = dn[rem];
    const int xm = max(x - 1, 0), xp = min(x + 1, 255);
    const int ym = max(y - 1, 0), yp = min(y + 1, 255);
    const int rm = ym << 8, r0 = y << 8, rp = yp << 8;
    const int a =
        (dn[rm + x ] < dp) + (dn[rp + x ] < dp) +
        (dn[r0 + xm] < dp) + (dn[r0 + xp] < dp);
    const int c =
        (dn[rm + xm] < dp) + (dn[rm + xp] < dp) +
        (dn[rp + xm] < dp) + (dn[rp + xp] < dp);
    const float W1 = expf(-(1.0f / 0.35f));          // edge weight
    const float W2 = expf(-(1.41421356f / 0.35f));   // corner weight (sqrt2 f32)
    float S = (float)a * W1 + (float)c * W2;         // >0 whenever dp>0
    float v = (float)(dp - 1) - 0.35f * logf(S);
    out[p] = (dp > 0) ? v : 0.0f;
}

extern "C" void kernel_launch(void* const* d_in, const int* in_sizes, int n_in,
                              void* d_out, int out_size, void* d_ws, size_t ws_size,
                              hipStream_t stream) {
    const float* img = (const float*)d_in[0];
    float* out = (float*)d_out;
    unsigned char* g = (unsigned char*)d_ws;   // 512 rows * 256 = 128 KiB
    unsigned char* d = g + (512 * 256);        // 128 KiB
    k_rowdt<<<512, 64, 0, stream>>>(img, g);
    k_cheb <<<512, 256, 0, stream>>>(g, d);
    k_out  <<<512, 256, 0, stream>>>(d, out);
}